// Round 5
// baseline (407.219 us; speedup 1.0000x reference)
//
#include <hip/hip_runtime.h>
#include <hip/hip_fp16.h>

typedef _Float16 f16;
typedef _Float16 f16x4 __attribute__((ext_vector_type(4)));
typedef _Float16 f16x8 __attribute__((ext_vector_type(8)));
typedef float f32x4 __attribute__((ext_vector_type(4)));

// B=2, T=2048, D=2048, NH=16, HD=128, Q_LAT=1024, KV_LAT=512
#define BT 4096
#define DMODEL 2048

__device__ __forceinline__ void gld16(const f16* g, f16* l) {
    __builtin_amdgcn_global_load_lds((const __attribute__((address_space(1))) void*)g,
                                     (__attribute__((address_space(3))) void*)l, 16, 0, 0);
}

// ---------------------------------------------------------------- fused fp32 -> fp16 (7 tensors, 1 launch)
struct Cvt7 {
    const float* s[7];
    f16* d[7];
    int off4[8];  // cumulative float4 counts
};
__global__ __launch_bounds__(256) void k_cvt7(Cvt7 c) {
    int i = blockIdx.x * 256 + threadIdx.x;
    if (i >= c.off4[7]) return;
    int seg = 0;
#pragma unroll
    for (int k = 1; k < 7; ++k) seg += (i >= c.off4[k]);
    int j = i - c.off4[seg];
    float4 v = ((const float4*)c.s[seg])[j];
    f16x4 h;
    h[0] = (f16)v.x; h[1] = (f16)v.y; h[2] = (f16)v.z; h[3] = (f16)v.w;
    ((f16x4*)c.d[seg])[j] = h;
}

// ---------------------------------------------------------------- plain GEMM: C[M,N] = A[M,K] @ B[N,K]^T (fp32 out)
template <typename CT>
__global__ __launch_bounds__(256, 3) void k_gemm_bt(const f16* __restrict__ A,
                                                    const f16* __restrict__ Bm,
                                                    CT* __restrict__ C,
                                                    int M, int N, int K) {
    __shared__ __align__(16) char smem[16384];
    f16* Als = (f16*)smem;
    f16* Bls = (f16*)(smem + 8192);
    const int tid = threadIdx.x;
    const int w = tid >> 6, l = tid & 63;
    const int quad = l >> 4, ln = l & 15;
    const int m0 = blockIdx.y * 128, n0 = blockIdx.x * 128;
    const int wm = (w >> 1) * 64, wn = (w & 1) * 64;
    const int srow = l >> 2, scol = (l & 3) * 8;

    f32x4 acc[4][4];
#pragma unroll
    for (int i = 0; i < 4; ++i)
#pragma unroll
        for (int j = 0; j < 4; ++j)
#pragma unroll
            for (int r = 0; r < 4; ++r) acc[i][j][r] = 0.f;

    for (int k0 = 0; k0 < K; k0 += 32) {
#pragma unroll
        for (int c = 0; c < 2; ++c) {
            const int ch = w + 4 * c;
            gld16(A + (size_t)(m0 + ch * 16 + srow) * K + (k0 + scol), &Als[ch * 512]);
            gld16(Bm + (size_t)(n0 + ch * 16 + srow) * K + (k0 + scol), &Bls[ch * 512]);
        }
        __syncthreads();
        f16x8 af[4], bf[4];
#pragma unroll
        for (int i = 0; i < 4; ++i) af[i] = *(const f16x8*)&Als[(wm + 16 * i + ln) * 32 + quad * 8];
#pragma unroll
        for (int j = 0; j < 4; ++j) bf[j] = *(const f16x8*)&Bls[(wn + 16 * j + ln) * 32 + quad * 8];
#pragma unroll
        for (int i = 0; i < 4; ++i)
#pragma unroll
            for (int j = 0; j < 4; ++j)
                acc[i][j] = __builtin_amdgcn_mfma_f32_16x16x32_f16(af[i], bf[j], acc[i][j], 0, 0, 0);
        __syncthreads();
    }
    const int p_w = (w >> 1) ? 16 : 0;
#pragma unroll
    for (int i = 0; i < 4; ++i) {
        if constexpr (sizeof(CT) == 2) {
            f16* Cs = (f16*)smem;  // [32][136]
#pragma unroll
            for (int j = 0; j < 4; ++j)
#pragma unroll
                for (int r = 0; r < 4; ++r)
                    Cs[(p_w + quad * 4 + r) * 136 + wn + 16 * j + ln] = (f16)acc[i][j][r];
            __syncthreads();
#pragma unroll
            for (int k2 = 0; k2 < 2; ++k2) {
                int idx = k2 * 256 + tid;
                int pr = idx >> 4, c = idx & 15;
                int rg = m0 + 16 * i + (pr & 15) + ((pr & 16) ? 64 : 0);
                *(f16x8*)&C[(size_t)rg * N + n0 + c * 8] = *(const f16x8*)&Cs[pr * 136 + c * 8];
            }
        } else {
            float* Cs = (float*)smem;  // [32][128]
#pragma unroll
            for (int j = 0; j < 4; ++j)
#pragma unroll
                for (int r = 0; r < 4; ++r)
                    Cs[(p_w + quad * 4 + r) * 128 + wn + 16 * j + ln] = acc[i][j][r];
            __syncthreads();
#pragma unroll
            for (int k2 = 0; k2 < 4; ++k2) {
                int idx = k2 * 256 + tid;
                int pr = idx >> 5, c = idx & 31;
                int rg = m0 + 16 * i + (pr & 15) + ((pr & 16) ? 64 : 0);
                *(float4*)&C[(size_t)rg * N + n0 + c * 4] = *(const float4*)&Cs[pr * 128 + c * 4];
            }
        }
        __syncthreads();
    }
}

// ---------------------------------------------------------------- dual-B / dual-C first-level GEMM
__global__ __launch_bounds__(256, 3) void k_gemm_dual(const f16* __restrict__ A,
                                                      const f16* __restrict__ B0,
                                                      const f16* __restrict__ B1,
                                                      f16* __restrict__ C0, f16* __restrict__ C1,
                                                      int K, int nsplit, int ld0, int ld1) {
    __shared__ __align__(16) char smem[16384];
    f16* Als = (f16*)smem;
    f16* Bls = (f16*)(smem + 8192);
    const int tid = threadIdx.x;
    const int w = tid >> 6, l = tid & 63;
    const int quad = l >> 4, ln = l & 15;
    const int m0 = blockIdx.y * 128, n0 = blockIdx.x * 128;
    const int wm = (w >> 1) * 64, wn = (w & 1) * 64;
    const int srow = l >> 2, scol = (l & 3) * 8;
    const f16* Bm = (n0 < nsplit) ? B0 + (size_t)n0 * K : B1 + (size_t)(n0 - nsplit) * K;

    f32x4 acc[4][4];
#pragma unroll
    for (int i = 0; i < 4; ++i)
#pragma unroll
        for (int j = 0; j < 4; ++j)
#pragma unroll
            for (int r = 0; r < 4; ++r) acc[i][j][r] = 0.f;

    for (int k0 = 0; k0 < K; k0 += 32) {
#pragma unroll
        for (int c = 0; c < 2; ++c) {
            const int ch = w + 4 * c;
            gld16(A + (size_t)(m0 + ch * 16 + srow) * K + (k0 + scol), &Als[ch * 512]);
            gld16(Bm + (size_t)(ch * 16 + srow) * K + (k0 + scol), &Bls[ch * 512]);
        }
        __syncthreads();
        f16x8 af[4], bf[4];
#pragma unroll
        for (int i = 0; i < 4; ++i) af[i] = *(const f16x8*)&Als[(wm + 16 * i + ln) * 32 + quad * 8];
#pragma unroll
        for (int j = 0; j < 4; ++j) bf[j] = *(const f16x8*)&Bls[(wn + 16 * j + ln) * 32 + quad * 8];
#pragma unroll
        for (int i = 0; i < 4; ++i)
#pragma unroll
            for (int j = 0; j < 4; ++j)
                acc[i][j] = __builtin_amdgcn_mfma_f32_16x16x32_f16(af[i], bf[j], acc[i][j], 0, 0, 0);
        __syncthreads();
    }
    f16* Cd; int ldc, cb;
    if (n0 < nsplit) { Cd = C0; ldc = ld0; cb = n0; }
    else             { Cd = C1; ldc = ld1; cb = n0 - nsplit; }
    const int p_w = (w >> 1) ? 16 : 0;
    f16* Cs = (f16*)smem;  // [32][136]
#pragma unroll
    for (int i = 0; i < 4; ++i) {
#pragma unroll
        for (int j = 0; j < 4; ++j)
#pragma unroll
            for (int r = 0; r < 4; ++r)
                Cs[(p_w + quad * 4 + r) * 136 + wn + 16 * j + ln] = (f16)acc[i][j][r];
        __syncthreads();
#pragma unroll
        for (int k2 = 0; k2 < 2; ++k2) {
            int idx = k2 * 256 + tid;
            int pr = idx >> 4, c = idx & 15;
            int rg = m0 + 16 * i + (pr & 15) + ((pr & 16) ? 64 : 0);
            *(f16x8*)&Cd[(size_t)rg * ldc + cb + c * 8] = *(const f16x8*)&Cs[pr * 136 + c * 8];
        }
        __syncthreads();
    }
}

// ---------------------------------------------------------------- merged second-level GEMM (1536 blocks):
// region 0 (bx 0..15):  qpre = qlat @ wqb^T   (K=1024)
// region 1 (bx 16..31): kpre = kvb @ wkb^T    (K=512)
// region 2 (bx 32..47): vt   = (kvb @ wvb^T)^T per batch (K=512)
__global__ __launch_bounds__(256, 3) void k_gemm3(const f16* __restrict__ qlat,
                                                  const f16* __restrict__ kvb,
                                                  const f16* __restrict__ wqb,
                                                  const f16* __restrict__ wkb,
                                                  const f16* __restrict__ wvb,
                                                  f16* __restrict__ qpre,
                                                  f16* __restrict__ kpre,
                                                  f16* __restrict__ vt) {
    __shared__ __align__(16) char smem[16384];
    f16* Als = (f16*)smem;
    f16* Bls = (f16*)(smem + 8192);
    const int tid = threadIdx.x;
    const int w = tid >> 6, l = tid & 63;
    const int quad = l >> 4, ln = l & 15;
    const int m0 = blockIdx.y * 128;
    const int bx = blockIdx.x;
    const int region = bx >> 4;
    const int n0 = (bx & 15) * 128;
    const int wm = (w >> 1) * 64, wn = (w & 1) * 64;
    const int srow = l >> 2, scol = (l & 3) * 8;

    const f16* A;
    const f16* Bm;
    int K;
    if (region == 0)      { A = qlat; Bm = wqb + (size_t)n0 * 1024; K = 1024; }
    else if (region == 1) { A = kvb;  Bm = wkb + (size_t)n0 * 512;  K = 512; }
    else                  { A = kvb;  Bm = wvb + (size_t)n0 * 512;  K = 512; }

    f32x4 acc[4][4];
#pragma unroll
    for (int i = 0; i < 4; ++i)
#pragma unroll
        for (int j = 0; j < 4; ++j)
#pragma unroll
            for (int r = 0; r < 4; ++r) acc[i][j][r] = 0.f;

    for (int k0 = 0; k0 < K; k0 += 32) {
#pragma unroll
        for (int c = 0; c < 2; ++c) {
            const int ch = w + 4 * c;
            gld16(A + (size_t)(m0 + ch * 16 + srow) * K + (k0 + scol), &Als[ch * 512]);
            gld16(Bm + (size_t)(ch * 16 + srow) * K + (k0 + scol), &Bls[ch * 512]);
        }
        __syncthreads();
        f16x8 af[4], bf[4];
#pragma unroll
        for (int i = 0; i < 4; ++i) af[i] = *(const f16x8*)&Als[(wm + 16 * i + ln) * 32 + quad * 8];
#pragma unroll
        for (int j = 0; j < 4; ++j) bf[j] = *(const f16x8*)&Bls[(wn + 16 * j + ln) * 32 + quad * 8];
#pragma unroll
        for (int i = 0; i < 4; ++i)
#pragma unroll
            for (int j = 0; j < 4; ++j)
                acc[i][j] = __builtin_amdgcn_mfma_f32_16x16x32_f16(af[i], bf[j], acc[i][j], 0, 0, 0);
        __syncthreads();
    }
    const int p_w = (w >> 1) ? 16 : 0;
    f16* Cs = (f16*)smem;  // [32][136]
    const int bb = m0 >> 11, tb = m0 & 2047;
#pragma unroll
    for (int i = 0; i < 4; ++i) {
#pragma unroll
        for (int j = 0; j < 4; ++j)
#pragma unroll
            for (int r = 0; r < 4; ++r)
                Cs[(p_w + quad * 4 + r) * 136 + wn + 16 * j + ln] = (f16)acc[i][j][r];
        __syncthreads();
        if (region < 2) {
            f16* Cd = region ? kpre : qpre;
#pragma unroll
            for (int k2 = 0; k2 < 2; ++k2) {
                int idx = k2 * 256 + tid;
                int pr = idx >> 4, c = idx & 15;
                int rg = m0 + 16 * i + (pr & 15) + ((pr & 16) ? 64 : 0);
                *(f16x8*)&Cd[(size_t)rg * 2048 + n0 + c * 8] = *(const f16x8*)&Cs[pr * 136 + c * 8];
            }
        } else {
#pragma unroll
            for (int it = 0; it < 2; ++it) {
                int idx = it * 256 + tid;
                int d = idx & 127, tc = (idx >> 7) & 1, g = idx >> 8;
                f16x8 v;
#pragma unroll
                for (int k = 0; k < 8; ++k) v[k] = Cs[(g * 16 + tc * 8 + k) * 136 + d];
                int t = tb + 16 * i + g * 64 + tc * 8;
                *(f16x8*)&vt[((size_t)(bb * 2048 + n0 + d)) * 2048 + t] = v;
            }
        }
        __syncthreads();
    }
}

// ---------------------------------------------------------------- RMSNorm + RoPE (in place, vectorized)
// 32 lanes per (row,head); lane j owns dims 4j..4j+3; rotate_half partner via shfl_xor(16).
__global__ __launch_bounds__(256) void k_norm_rope(f16* __restrict__ q, f16* __restrict__ k,
                                                   const float* __restrict__ qw,
                                                   const float* __restrict__ kw) {
    const int tid = threadIdx.x;
    const int id = blockIdx.x * 8 + (tid >> 5);   // rowhead id 0..131071
    const int j = tid & 31;
    const int which = id >> 16;                    // 0=q, 1=k
    const int rh = id & 65535;
    const int row = rh >> 4, h = rh & 15;
    f16* p = which ? k : q;
    const float* wp = which ? kw : qw;
    const float scale = which ? 1.0f : 0.12751743f;  // (1/sqrt(128))*log2(e) folded into q
    const size_t base = (size_t)row * DMODEL + h * 128;
    f16x4 xv = *(const f16x4*)&p[base + 4 * j];
    float x0 = (float)xv[0], x1 = (float)xv[1], x2 = (float)xv[2], x3 = (float)xv[3];
    float ss = x0 * x0 + x1 * x1 + x2 * x2 + x3 * x3;
#pragma unroll
    for (int off = 16; off > 0; off >>= 1) ss += __shfl_xor(ss, off);
    const float rms = rsqrtf(ss * (1.0f / 128.0f) + 1e-6f);
    float4 wv = *(const float4*)&wp[4 * j];
    float n0 = x0 * rms * wv.x, n1 = x1 * rms * wv.y, n2 = x2 * rms * wv.z, n3 = x3 * rms * wv.w;
    float p0 = __shfl_xor(n0, 16), p1 = __shfl_xor(n1, 16), p2 = __shfl_xor(n2, 16), p3 = __shfl_xor(n3, 16);
    const int t = row & 2047;
    const float sgn = (j < 16) ? -1.f : 1.f;
    const int fi = (4 * j) & 63;
    float nv[4] = {n0, n1, n2, n3}, pv[4] = {p0, p1, p2, p3};
    f16x4 o;
#pragma unroll
    for (int c = 0; c < 4; ++c) {
        const float fr = exp2f(-0.20762051f * (float)(fi + c));  // log2(10000)/64
        const float ang = (float)t * fr;
        o[c] = (f16)((nv[c] * cosf(ang) + sgn * pv[c] * sinf(ang)) * scale);
    }
    *(f16x4*)&p[base + 4 * j] = o;
}

// ---------------------------------------------------------------- flash attention, causal, BM=64 BN=64
// S^T trick: S^T = K·Q^T so P lands in-register in 16x16x16 A-operand layout (no LDS roundtrip).
// exp2-domain softmax (log2e folded into q scale).
__global__ __launch_bounds__(256, 3) void k_flash(const f16* __restrict__ Q, const f16* __restrict__ K,
                                                  const f16* __restrict__ Vt, f16* __restrict__ O) {
    __shared__ f16 Kl[64 * 136];   // [t_k][d]
    __shared__ f16 Vl[128 * 72];   // [d][t_k]
    const int h = blockIdx.x, b = blockIdx.y, mt = 31 - blockIdx.z;
    const int tid = threadIdx.x, w = tid >> 6, l64 = tid & 63;
    const int quad = l64 >> 4, ln = l64 & 15;

    f16x8 qf[4];
    {
        const int tq = mt * 64 + w * 16 + ln;
        const f16* qp = Q + (size_t)(b * 2048 + tq) * DMODEL + h * 128 + quad * 8;
#pragma unroll
        for (int kc = 0; kc < 4; ++kc) qf[kc] = *(const f16x8*)(qp + kc * 32);
    }
    f32x4 oacc[8];
#pragma unroll
    for (int ot = 0; ot < 8; ++ot)
#pragma unroll
        for (int r = 0; r < 4; ++r) oacc[ot][r] = 0.f;
    float m_r = -INFINITY, l_r = 0.f;  // per-lane: row q = ln (log2 domain)

    const f16* kbase = K + (size_t)(b * 2048) * DMODEL + h * 128;
    const f16* vbase = Vt + (size_t)(b * 2048 + h * 128) * 2048;

    f16x8 kr[4], vr[4];
#pragma unroll
    for (int c = 0; c < 4; ++c) {
        int idx = c * 256 + tid;
        kr[c] = *(const f16x8*)(kbase + (size_t)(idx >> 4) * DMODEL + (idx & 15) * 8);
        vr[c] = *(const f16x8*)(vbase + (size_t)(idx >> 3) * 2048 + (idx & 7) * 8);
    }

    for (int j = 0; j <= mt; ++j) {
        __syncthreads();
#pragma unroll
        for (int c = 0; c < 4; ++c) {
            int idx = c * 256 + tid;
            *(f16x8*)&Kl[(idx >> 4) * 136 + (idx & 15) * 8] = kr[c];
            *(f16x8*)&Vl[(idx >> 3) * 72 + (idx & 7) * 8] = vr[c];
        }
        __syncthreads();
        if (j < mt) {
#pragma unroll
            for (int c = 0; c < 4; ++c) {
                int idx = c * 256 + tid;
                kr[c] = *(const f16x8*)(kbase + (size_t)((j + 1) * 64 + (idx >> 4)) * DMODEL + (idx & 15) * 8);
                vr[c] = *(const f16x8*)(vbase + (size_t)(idx >> 3) * 2048 + (j + 1) * 64 + (idx & 7) * 8);
            }
        }
        // S^T = K Q^T : C row=t_k(quad*4+r), col=q(ln)
        f32x4 sacc[4];
#pragma unroll
        for (int nt = 0; nt < 4; ++nt)
#pragma unroll
            for (int r = 0; r < 4; ++r) sacc[nt][r] = 0.f;
#pragma unroll
        for (int nt = 0; nt < 4; ++nt)
#pragma unroll
            for (int kc = 0; kc < 4; ++kc) {
                f16x8 kf = *(const f16x8*)&Kl[(nt * 16 + ln) * 136 + kc * 32 + quad * 8];
                sacc[nt] = __builtin_amdgcn_mfma_f32_16x16x32_f16(kf, qf[kc], sacc[nt], 0, 0, 0);
            }
        if (j == mt) {  // diagonal: mask k > q
#pragma unroll
            for (int nt = 0; nt < 4; ++nt)
#pragma unroll
                for (int r = 0; r < 4; ++r)
                    if (nt * 16 + quad * 4 + r > w * 16 + ln) sacc[nt][r] = -INFINITY;
        }
        // online softmax (log2 domain): lane owns its whole row, reduce across quads
        float mx = -INFINITY;
#pragma unroll
        for (int nt = 0; nt < 4; ++nt)
#pragma unroll
            for (int r = 0; r < 4; ++r) mx = fmaxf(mx, sacc[nt][r]);
        mx = fmaxf(mx, __shfl_xor(mx, 16));
        mx = fmaxf(mx, __shfl_xor(mx, 32));
        const float mn = fmaxf(m_r, mx);
        const float alpha = exp2f(m_r - mn);
        m_r = mn;
        f16x4 pa[4];
        float s0 = 0.f;
#pragma unroll
        for (int nt = 0; nt < 4; ++nt)
#pragma unroll
            for (int r = 0; r < 4; ++r) {
                float pv = exp2f(sacc[nt][r] - mn);
                s0 += pv;
                pa[nt][r] = (f16)pv;
            }
        s0 += __shfl_xor(s0, 16);
        s0 += __shfl_xor(s0, 32);
        l_r = l_r * alpha + s0;
        float ar[4];
#pragma unroll
        for (int r = 0; r < 4; ++r) ar[r] = __shfl(alpha, (l64 & 48) | (quad * 4 + r));
#pragma unroll
        for (int ot = 0; ot < 8; ++ot)
#pragma unroll
            for (int r = 0; r < 4; ++r) oacc[ot][r] *= ar[r];
        // O += P @ V via 16x16x16 (P in A-layout in registers)
#pragma unroll
        for (int nt = 0; nt < 4; ++nt)
#pragma unroll
            for (int ot = 0; ot < 8; ++ot) {
                f16x4 vf = *(const f16x4*)&Vl[(ot * 16 + ln) * 72 + nt * 16 + quad * 4];
                oacc[ot] = __builtin_amdgcn_mfma_f32_16x16x16f16(pa[nt], vf, oacc[ot], 0, 0, 0);
            }
    }
    const float inv = 1.0f / l_r;
    float ivr[4];
#pragma unroll
    for (int r = 0; r < 4; ++r) ivr[r] = __shfl(inv, (l64 & 48) | (quad * 4 + r));
    __syncthreads();
#pragma unroll
    for (int ot = 0; ot < 8; ++ot)
#pragma unroll
        for (int r = 0; r < 4; ++r)
            Kl[(w * 16 + quad * 4 + r) * 136 + ot * 16 + ln] = (f16)(oacc[ot][r] * ivr[r]);
    __syncthreads();
#pragma unroll
    for (int c = 0; c < 4; ++c) {
        int idx = c * 256 + tid;
        int row = idx >> 4, col8 = (idx & 15) * 8;
        *(f16x8*)&O[(size_t)(b * 2048 + mt * 64 + row) * DMODEL + h * 128 + col8] =
            *(const f16x8*)&Kl[row * 136 + col8];
    }
}

// ----------------------------------------------------------------
extern "C" void kernel_launch(void* const* d_in, const int* in_sizes, int n_in,
                              void* d_out, int out_size, void* d_ws, size_t ws_size,
                              hipStream_t stream) {
    const float* x    = (const float*)d_in[0];
    const float* qaw  = (const float*)d_in[2];
    const float* qbw  = (const float*)d_in[3];
    const float* kvaw = (const float*)d_in[4];
    const float* kbw  = (const float*)d_in[5];
    const float* vbw  = (const float*)d_in[6];
    const float* ow   = (const float*)d_in[7];
    const float* qnw  = (const float*)d_in[8];
    const float* knw  = (const float*)d_in[9];
    float* out = (float*)d_out;

    char* p = (char*)d_ws;
    auto alloc = [&](size_t elems) { f16* r = (f16*)p; p += elems * sizeof(f16); return r; };
    f16* xb   = alloc((size_t)BT * 2048);     // reused as vt
    f16* wo   = alloc((size_t)2048 * 2048);
    f16* wqa  = alloc((size_t)1024 * 2048);   // attn overlay starts here
    f16* wqb  = alloc((size_t)2048 * 1024);
    f16* wkva = alloc((size_t)512 * 2048);
    f16* wkb  = alloc((size_t)2048 * 512);
    f16* wvb  = alloc((size_t)2048 * 512);
    f16* qlat = alloc((size_t)BT * 1024);
    f16* kvb  = alloc((size_t)BT * 512);
    f16* qpre = alloc((size_t)BT * 2048);
    f16* kpre = alloc((size_t)BT * 2048);
    f16* vt   = xb;    // [b][d][t], written by k_gemm3 after xb consumed
    f16* attn = wqa;   // overlays weight region, free post-GEMMs

    Cvt7 c;
    c.s[0] = x;    c.d[0] = xb;
    c.s[1] = qaw;  c.d[1] = wqa;
    c.s[2] = qbw;  c.d[2] = wqb;
    c.s[3] = kvaw; c.d[3] = wkva;
    c.s[4] = kbw;  c.d[4] = wkb;
    c.s[5] = vbw;  c.d[5] = wvb;
    c.s[6] = ow;   c.d[6] = wo;
    int sz4[7] = {BT * 2048 / 4, 1024 * 2048 / 4, 2048 * 1024 / 4, 512 * 2048 / 4,
                  2048 * 512 / 4, 2048 * 512 / 4, 2048 * 2048 / 4};
    c.off4[0] = 0;
    for (int i = 0; i < 7; ++i) c.off4[i + 1] = c.off4[i] + sz4[i];
    k_cvt7<<<(c.off4[7] + 255) / 256, 256, 0, stream>>>(c);

    dim3 blk(256);
    // qlat = xb@wqa^T ; kvb = xb@wkva^T  (merged, 384 blocks)
    k_gemm_dual<<<dim3(1536 / 128, BT / 128), blk, 0, stream>>>(xb, wqa, wkva, qlat, kvb, 2048, 1024, 1024, 512);
    // qpre / kpre / vt in ONE launch (1536 blocks = 2 full occupancy waves)
    k_gemm3<<<dim3(48, BT / 128), blk, 0, stream>>>(qlat, kvb, wqb, wkb, wvb, qpre, kpre, vt);
    // rmsnorm + rope in place (vectorized)
    k_norm_rope<<<16384, 256, 0, stream>>>(qpre, kpre, qnw, knw);
    // flash attention
    k_flash<<<dim3(16, 2, 32), 256, 0, stream>>>(qpre, kpre, vt, attn);
    // out = attn@wo^T (fp32)
    k_gemm_bt<float><<<dim3(2048 / 128, BT / 128), blk, 0, stream>>>(attn, wo, out, BT, 2048, 2048);
}